// Round 21
// baseline (175.238 us; speedup 1.0000x reference)
//
#include <hip/hip_runtime.h>
#include <hip/hip_bf16.h>
#include <math.h>

#define NN 50000
#define NE 1600000
#define FIN 128
#define EH 20
#define DH 64

#define BSTEP 64                        // nodes per bucket
#define NBK ((NN + BSTEP - 1) / BSTEP)  // 782 buckets
#define BCAP 3072                       // fixed record capacity per bucket (mean 2048)
#define CHUNK 2048                      // edges per binning block (R20 lesson: 8192 -> <1 block/CU)
#define PERT (CHUNK / 256)              // 8 edges per thread
#define ESPLIT 4                        // blocks per bucket in k_edge_b
#define WPAD 132                        // LDS row pitch for W^T staging in k_xw

// ---------------- kernels ----------------

// init bucket cursors, off[NN]=NE, detect ei width
__global__ void k_init(int* bcur, int* off, int* flag, const void* ei) {
    int i = threadIdx.x;
    for (int b = i; b < NBK; b += 1024) bcur[b] = b * BCAP;
    if (i == 0) {
        off[NN] = NE;
        const int* w = (const int*)ei;
        int all0 = 1;
        for (int j = 1; j < 128; j += 2) all0 &= (w[j] == 0);
        *flag = all0;  // 1 => int64 layout (high words zero), 0 => int32
    }
}

__device__ __forceinline__ int ld_col(const void* ei, int w64, size_t idx) {
    return w64 ? (int)((const long long*)ei)[idx] : ((const int*)ei)[idx];
}

// binned fill straight from ei into fixed per-bucket regions:
// packed records (r | c_local<<16) grouped by bucket; pos32[e] = record slot.
__global__ void k_bin(const void* ei, const int* flag,
                      int* __restrict__ bcur, unsigned* __restrict__ binned,
                      int* __restrict__ pos32) {
    __shared__ int hist[NBK];
    __shared__ int gbase[NBK];
    const int base = blockIdx.x * CHUNK;
    for (int i = threadIdx.x; i < NBK; i += 256) hist[i] = 0;
    __syncthreads();
    const int w64 = *flag;
    int myr[PERT], myc[PERT];
#pragma unroll
    for (int i = 0; i < PERT; ++i) {
        int idx = base + threadIdx.x + i * 256;
        if (idx < NE) {
            myr[i] = ld_col(ei, w64, idx);
            int c = ld_col(ei, w64, (size_t)NE + idx);
            myc[i] = c;
            atomicAdd(&hist[c >> 6], 1);
        } else {
            myc[i] = -1;
        }
    }
    __syncthreads();
    for (int b = threadIdx.x; b < NBK; b += 256) {
        int h = hist[b];
        gbase[b] = h ? atomicAdd(&bcur[b], h) : 0;
        hist[b] = 0;  // reuse as local cursor
    }
    __syncthreads();
#pragma unroll
    for (int i = 0; i < PERT; ++i) {
        int c = myc[i];
        if (c >= 0) {
            int bkt = c >> 6;
            int pos = gbase[bkt] + atomicAdd(&hist[bkt], 1);
            binned[pos] = (unsigned)myr[i] | ((unsigned)(c & 63) << 16);
            pos32[base + threadIdx.x + i * 256] = pos;
        }
    }
}

// per-bucket: derive global base (reduce over bcur), per-node offsets (LDS
// hist + scan), write off[], scatter src[] grouped by node.
__global__ void k_sort(const int* __restrict__ bcur, const unsigned* __restrict__ binned,
                       int* __restrict__ off, int* __restrict__ src) {
    __shared__ int red[256];
    __shared__ int hcnt[BSTEP];
    __shared__ int sc[BSTEP];
    __shared__ int hoff[BSTEP];
    __shared__ int cur[BSTEP];
    const int b = blockIdx.x;
    const int nbase = b * BSTEP;
    // p0 = sum_{i<b} (bcur[i] - i*BCAP)
    int part = 0;
    for (int i = threadIdx.x; i < b; i += 256) part += bcur[i] - i * BCAP;
    red[threadIdx.x] = part;
    __syncthreads();
    for (int d = 128; d > 0; d >>= 1) {
        if (threadIdx.x < d) red[threadIdx.x] += red[threadIdx.x + d];
        __syncthreads();
    }
    const int p0 = red[0];
    const int cnt = bcur[b] - b * BCAP;
    const unsigned* rbase = binned + (size_t)b * BCAP;
    if (threadIdx.x < BSTEP) hcnt[threadIdx.x] = 0;
    __syncthreads();
    // pass 1: per-node counts
    for (int i = threadIdx.x; i < cnt; i += 256)
        atomicAdd(&hcnt[rbase[i] >> 16], 1);
    __syncthreads();
    int v = 0;
    if (threadIdx.x < BSTEP) { v = hcnt[threadIdx.x]; sc[threadIdx.x] = v; }
    __syncthreads();
    for (int d = 1; d < BSTEP; d <<= 1) {
        int u = 0;
        if (threadIdx.x < BSTEP && threadIdx.x >= d) u = sc[threadIdx.x - d];
        __syncthreads();
        if (threadIdx.x < BSTEP) sc[threadIdx.x] += u;
        __syncthreads();
    }
    if (threadIdx.x < BSTEP) {
        int o = p0 + sc[threadIdx.x] - v;  // exclusive
        hoff[threadIdx.x] = o;
        cur[threadIdx.x] = 0;
        int n = nbase + threadIdx.x;
        if (n < NN) off[n] = o;
    }
    __syncthreads();
    // pass 2: scatter grouped by node
    for (int i = threadIdx.x; i < cnt; i += 256) {
        unsigned rec = rbase[i];
        int cl = rec >> 16;
        int pos = hoff[cl] + atomicAdd(&cur[cl], 1);
        src[pos] = (int)(rec & 0xffffu);
    }
}

// hs16[n*32+k] = bf16(dinv[n] * dot(x[n,:], W[:,k])).
// W staged per block into LDS transposed (pitch 132 — no sector blowup, R18
// lesson); each thread handles k for TWO nodes (R19/R20 lesson: load-issue bound).
__global__ void k_xw(const float* __restrict__ x, const float* __restrict__ W,
                     const int* __restrict__ off, __hip_bfloat16* __restrict__ hs16) {
    __shared__ float wt[EH * WPAD];  // 10560 B
    for (int p = threadIdx.x; p < FIN * EH; p += 256) {
        int j = p / EH, k = p - j * EH;   // p = j*EH + k (coalesced global read)
        wt[k * WPAD + j] = W[p];
    }
    __syncthreads();
    int t = blockIdx.x * blockDim.x + threadIdx.x;
    int g = t / EH;             // node-pair index
    int k = t - g * EH;
    int n0 = g * 2;
    if (n0 >= NN) return;       // NN even -> n0+1 < NN whenever n0 < NN
    const float4* xr0 = (const float4*)(x + (size_t)n0 * FIN);
    const float4* xr1 = (const float4*)(x + (size_t)(n0 + 1) * FIN);
    const float4* wr = (const float4*)(wt + k * WPAD);
    float a00 = 0.f, a01 = 0.f, a10 = 0.f, a11 = 0.f;
#pragma unroll 4
    for (int j4 = 0; j4 < FIN / 4; j4 += 2) {
        float4 w0 = wr[j4];
        float4 w1 = wr[j4 + 1];
        float4 p0 = xr0[j4];
        float4 p1 = xr0[j4 + 1];
        float4 q0 = xr1[j4];
        float4 q1 = xr1[j4 + 1];
        a00 = fmaf(p0.x, w0.x, a00); a00 = fmaf(p0.y, w0.y, a00);
        a00 = fmaf(p0.z, w0.z, a00); a00 = fmaf(p0.w, w0.w, a00);
        a01 = fmaf(p1.x, w1.x, a01); a01 = fmaf(p1.y, w1.y, a01);
        a01 = fmaf(p1.z, w1.z, a01); a01 = fmaf(p1.w, w1.w, a01);
        a10 = fmaf(q0.x, w0.x, a10); a10 = fmaf(q0.y, w0.y, a10);
        a10 = fmaf(q0.z, w0.z, a10); a10 = fmaf(q0.w, w0.w, a10);
        a11 = fmaf(q1.x, w1.x, a11); a11 = fmaf(q1.y, w1.y, a11);
        a11 = fmaf(q1.z, w1.z, a11); a11 = fmaf(q1.w, w1.w, a11);
    }
    float d0 = rsqrtf(1.0f + (float)(off[n0 + 1] - off[n0]));
    float d1 = rsqrtf(1.0f + (float)(off[n0 + 2] - off[n0 + 1]));
    hs16[(size_t)n0 * 32 + k]       = __float2bfloat16(d0 * (a00 + a01));
    hs16[(size_t)(n0 + 1) * 32 + k] = __float2bfloat16(d1 * (a10 + a11));
}

__device__ __forceinline__ float blo(unsigned u) { return __uint_as_float(u << 16); }
__device__ __forceinline__ float bhi(unsigned u) { return __uint_as_float(u & 0xffff0000u); }

// per-node gather + bias + relu; 5 lanes per node, each lane owns 4 feature
// slots via one uint2 (8B) load per edge — halves load-instruction count vs
// the 10-lane version (load-issue bound, R19/R20 lesson); zero atomics.
__global__ void k_gather(const int* __restrict__ off, const int* __restrict__ src,
                         const __hip_bfloat16* __restrict__ hs16,
                         const float* __restrict__ bg, float* __restrict__ h1) {
    int t = blockIdx.x * blockDim.x + threadIdx.x;
    int n = t / 5;
    int kk = t - n * 5;      // feature quad index: handles k=4kk..4kk+3
    if (n >= NN) return;
    const uint2* hu = (const uint2*)hs16;  // row stride 8 uint2 (32 bf16 = 64B)
    uint2 self = hu[n * 8 + kk];
    float a0 = blo(self.x), a1 = bhi(self.x);
    float a2 = blo(self.y), a3 = bhi(self.y);
    int e0 = off[n], e1 = off[n + 1];
    int e = e0;
    for (; e + 3 < e1; e += 4) {
        int r0 = src[e];       // broadcast across the 5-lane group
        int r1 = src[e + 1];
        int r2 = src[e + 2];
        int r3 = src[e + 3];
        uint2 v0 = hu[r0 * 8 + kk];
        uint2 v1 = hu[r1 * 8 + kk];
        uint2 v2 = hu[r2 * 8 + kk];
        uint2 v3 = hu[r3 * 8 + kk];
        a0 += blo(v0.x); a1 += bhi(v0.x); a2 += blo(v0.y); a3 += bhi(v0.y);
        a0 += blo(v1.x); a1 += bhi(v1.x); a2 += blo(v1.y); a3 += bhi(v1.y);
        a0 += blo(v2.x); a1 += bhi(v2.x); a2 += blo(v2.y); a3 += bhi(v2.y);
        a0 += blo(v3.x); a1 += bhi(v3.x); a2 += blo(v3.y); a3 += bhi(v3.y);
    }
    for (; e < e1; ++e) {
        uint2 v = hu[src[e] * 8 + kk];
        a0 += blo(v.x); a1 += bhi(v.x); a2 += blo(v.y); a3 += bhi(v.y);
    }
    float dinv = rsqrtf(1.0f + (float)(e1 - e0));
    float4 res;
    res.x = fmaxf(fmaf(dinv, a0, bg[4 * kk + 0]), 0.f);
    res.y = fmaxf(fmaf(dinv, a1, bg[4 * kk + 1]), 0.f);
    res.z = fmaxf(fmaf(dinv, a2, bg[4 * kk + 2]), 0.f);
    res.w = fmaxf(fmaf(dinv, a3, bg[4 * kk + 3]), 0.f);
    // h1 row pitch 20 floats = 80B; 80n + 16kk is 16B-aligned (80 = 16*5)
    *(float4*)(h1 + (size_t)n * EH + 4 * kk) = res;
}

// A16[n,j] = bf16(h1[n,:] @ W1[0:20, j]);
// B16[n,j] = bf16(b1[j] + h1[nid,:] @ W1[40:60, j] + h1[n,:] @ W1[20:40, j])
__global__ void k_ab(const float* __restrict__ h1, const float* __restrict__ W1,
                     const float* __restrict__ b1, const void* nid_p,
                     __hip_bfloat16* __restrict__ A16, __hip_bfloat16* __restrict__ B16) {
    int t = blockIdx.x * blockDim.x + threadIdx.x;
    int n = t >> 6;
    int j = t & 63;
    if (n >= NN) return;
    int nid = *(const int*)nid_p;  // low 32 bits valid for int32 or int64 LE
    const float* hr = h1 + (size_t)n * EH;
    const float* hn = h1 + (size_t)nid * EH;  // broadcast
    float a = 0.f, b = b1[j];
#pragma unroll
    for (int k = 0; k < EH; ++k) {
        float hv = hr[k];
        a = fmaf(hv, W1[k * DH + j], a);
        b = fmaf(hv, W1[(EH + k) * DH + j], b);
        b = fmaf(hn[k], W1[(2 * EH + k) * DH + j], b);
    }
    A16[(size_t)n * DH + j] = __float2bfloat16(a);
    B16[(size_t)n * DH + j] = __float2bfloat16(b);
}

// bucket-order edge dot: 4 lanes per record; B rows L1/L2-hot within bucket;
// writes relu-dot to stage[slot] (sequential). No ei/eps/transcendentals here.
__global__ void k_edge_b(const int* __restrict__ bcur,
                         const unsigned* __restrict__ binned,
                         const __hip_bfloat16* __restrict__ A16,
                         const __hip_bfloat16* __restrict__ B16,
                         const float* __restrict__ W2,
                         float* __restrict__ stage) {
    const int b = blockIdx.x / ESPLIT;
    const int part = blockIdx.x - b * ESPLIT;
    const int nbase = b * BSTEP;
    const int cnt = bcur[b] - b * BCAP;
    const unsigned* rbase = binned + (size_t)b * BCAP;
    float* sbase = stage + (size_t)b * BCAP;
    const int q = threadIdx.x & 3;
    const float* w = W2 + q * 16;
    for (int i = part * 64 + (threadIdx.x >> 2); i < cnt; i += 64 * ESPLIT) {
        unsigned rec = rbase[i];
        int r = (int)(rec & 0xffffu);
        int cl = (int)(rec >> 16);
        const uint4* arow = (const uint4*)(A16 + (size_t)r * DH) + q * 2;
        const uint4* brow = (const uint4*)(B16 + (size_t)(nbase + cl) * DH) + q * 2;
        float acc = 0.f;
#pragma unroll
        for (int j = 0; j < 2; ++j) {
            uint4 av = arow[j];
            uint4 bv = brow[j];
            acc = fmaf(fmaxf(blo(av.x) + blo(bv.x), 0.f), w[8 * j + 0], acc);
            acc = fmaf(fmaxf(bhi(av.x) + bhi(bv.x), 0.f), w[8 * j + 1], acc);
            acc = fmaf(fmaxf(blo(av.y) + blo(bv.y), 0.f), w[8 * j + 2], acc);
            acc = fmaf(fmaxf(bhi(av.y) + bhi(bv.y), 0.f), w[8 * j + 3], acc);
            acc = fmaf(fmaxf(blo(av.z) + blo(bv.z), 0.f), w[8 * j + 4], acc);
            acc = fmaf(fmaxf(bhi(av.z) + bhi(bv.z), 0.f), w[8 * j + 5], acc);
            acc = fmaf(fmaxf(blo(av.w) + blo(bv.w), 0.f), w[8 * j + 6], acc);
            acc = fmaf(fmaxf(bhi(av.w) + bhi(bv.w), 0.f), w[8 * j + 7], acc);
        }
        acc += __shfl_xor(acc, 1);
        acc += __shfl_xor(acc, 2);
        if (q == 0) sbase[i] = acc;
    }
}

// finalize in edge order: sequential eps/pos/out, random (cache-resident) stage read
__global__ void k_fin(const int* __restrict__ pos32, const float* __restrict__ stage,
                      const float* __restrict__ eps, const float* __restrict__ b2,
                      float* __restrict__ out) {
    int e = blockIdx.x * blockDim.x + threadIdx.x;
    if (e >= NE) return;
    float acc = stage[pos32[e]];
    float ep = eps[e];
    // ee = 0.9999 - 0.9998*ep ; 1-ee = 1e-4 + 0.9998*ep
    float ee = fmaf(-0.9998f, ep, 0.9999f);
    float om = fmaf(0.9998f, ep, 0.0001f);
    float gate = 0.69314718f * (__builtin_amdgcn_logf(ee) - __builtin_amdgcn_logf(om))
               + acc + b2[0];
    float tt = __builtin_amdgcn_exp2f(-1.44269504f * gate);
    out[e] = __builtin_amdgcn_rcpf(1.0f + tt);
}

// ---------------- launch ----------------

extern "C" void kernel_launch(void* const* d_in, const int* in_sizes, int n_in,
                              void* d_out, int out_size, void* d_ws, size_t ws_size,
                              hipStream_t stream) {
    const float* x   = (const float*)d_in[0];
    const void*  ei  = d_in[1];
    const void*  nid = d_in[2];
    const float* eps = (const float*)d_in[3];
    const float* Wg  = (const float*)d_in[4];
    const float* bg  = (const float*)d_in[5];
    const float* W1  = (const float*)d_in[6];
    const float* b1  = (const float*)d_in[7];
    const float* W2  = (const float*)d_in[8];
    const float* b2  = (const float*)d_in[9];
    float* out = (float*)d_out;

    float* ws = (float*)d_ws;
    // ALL offsets multiples of 256 floats (1 KiB): table rows stay
    // 64B-sector-aligned (R14/R15 lesson). Total ~13.06M floats = 52.3 MB.
    unsigned* binned = (unsigned*)(ws + 0);                   // 782*3072 = 2,402,304
    int*  src    = (int*)(ws + 2402560);                      // 1.6M
    int*  pos32  = (int*)(ws + 4002560);                      // 1.6M
    __hip_bfloat16* hs16 = (__hip_bfloat16*)(ws + 5602560);   // 0.8M floats
    float* h1    = ws + 6402560;                              // 1.0M (+pad)
    __hip_bfloat16* A16 = (__hip_bfloat16*)(ws + 7402752);    // 1.6M floats
    __hip_bfloat16* B16 = (__hip_bfloat16*)(ws + 9002752);    // 1.6M floats
    float* stage = ws + 10602752;                             // 2,402,304 (+pad)
    int* off     = (int*)(ws + 13005312);                     // NN+1
    int* bcur    = (int*)(ws + 13055744);                     // NBK
    int* flag    = (int*)(ws + 13056768);

    dim3 blk(256);
    const int nchunk = (NE + CHUNK - 1) / CHUNK;
    k_init<<<1, 1024, 0, stream>>>(bcur, off, flag, ei);
    k_bin<<<nchunk, blk, 0, stream>>>(ei, flag, bcur, binned, pos32);
    k_sort<<<NBK, blk, 0, stream>>>(bcur, binned, off, src);
    k_xw<<<((NN / 2) * EH + 255) / 256, blk, 0, stream>>>(x, Wg, off, hs16);
    k_gather<<<(NN * 5 + 255) / 256, blk, 0, stream>>>(off, src, hs16, bg, h1);
    k_ab<<<(NN * 64 + 255) / 256, blk, 0, stream>>>(h1, W1, b1, nid, A16, B16);
    k_edge_b<<<NBK * ESPLIT, blk, 0, stream>>>(bcur, binned, A16, B16, W2, stage);
    k_fin<<<(NE + 255) / 256, blk, 0, stream>>>(pos32, stage, eps, b2, out);
}

// Round 22
// 165.812 us; speedup vs baseline: 1.0568x; 1.0568x over previous
//
#include <hip/hip_runtime.h>
#include <hip/hip_bf16.h>
#include <math.h>

#define NN 50000
#define NE 1600000
#define FIN 128
#define EH 20
#define DH 64

#define BSTEP 64                        // nodes per bucket
#define NBK ((NN + BSTEP - 1) / BSTEP)  // 782 buckets
#define BCAP 3072                       // fixed record capacity per bucket (mean 2048)
#define CHUNK 4096                      // edges per binning block (R21: 2048 too small, R20: 8192 <1 blk/CU)
#define PERT (CHUNK / 256)              // 16 edges per thread
#define ESPLIT 4                        // blocks per bucket in k_edge_b
#define WPAD 132                        // LDS row pitch for W^T staging in k_xw

// ---------------- kernels ----------------

// init bucket cursors, off[NN]=NE, detect ei width
__global__ void k_init(int* bcur, int* off, int* flag, const void* ei) {
    int i = threadIdx.x;
    for (int b = i; b < NBK; b += 1024) bcur[b] = b * BCAP;
    if (i == 0) {
        off[NN] = NE;
        const int* w = (const int*)ei;
        int all0 = 1;
        for (int j = 1; j < 128; j += 2) all0 &= (w[j] == 0);
        *flag = all0;  // 1 => int64 layout (high words zero), 0 => int32
    }
}

__device__ __forceinline__ int ld_col(const void* ei, int w64, size_t idx) {
    return w64 ? (int)((const long long*)ei)[idx] : ((const int*)ei)[idx];
}

// binned fill straight from ei into fixed per-bucket regions:
// packed records (r | c_local<<16) grouped by bucket; pos32[e] = record slot.
__global__ void k_bin(const void* ei, const int* flag,
                      int* __restrict__ bcur, unsigned* __restrict__ binned,
                      int* __restrict__ pos32) {
    __shared__ int hist[NBK];
    __shared__ int gbase[NBK];
    const int base = blockIdx.x * CHUNK;
    for (int i = threadIdx.x; i < NBK; i += 256) hist[i] = 0;
    __syncthreads();
    const int w64 = *flag;
    int myr[PERT], myc[PERT];
#pragma unroll
    for (int i = 0; i < PERT; ++i) {
        int idx = base + threadIdx.x + i * 256;
        if (idx < NE) {
            myr[i] = ld_col(ei, w64, idx);
            int c = ld_col(ei, w64, (size_t)NE + idx);
            myc[i] = c;
            atomicAdd(&hist[c >> 6], 1);
        } else {
            myc[i] = -1;
        }
    }
    __syncthreads();
    for (int b = threadIdx.x; b < NBK; b += 256) {
        int h = hist[b];
        gbase[b] = h ? atomicAdd(&bcur[b], h) : 0;
        hist[b] = 0;  // reuse as local cursor
    }
    __syncthreads();
#pragma unroll
    for (int i = 0; i < PERT; ++i) {
        int c = myc[i];
        if (c >= 0) {
            int bkt = c >> 6;
            int pos = gbase[bkt] + atomicAdd(&hist[bkt], 1);
            binned[pos] = (unsigned)myr[i] | ((unsigned)(c & 63) << 16);
            pos32[base + threadIdx.x + i * 256] = pos;
        }
    }
}

// per-bucket: derive global base (reduce over bcur), per-node offsets (LDS
// hist + scan), write off[], scatter src[] grouped by node.
__global__ void k_sort(const int* __restrict__ bcur, const unsigned* __restrict__ binned,
                       int* __restrict__ off, int* __restrict__ src) {
    __shared__ int red[256];
    __shared__ int hcnt[BSTEP];
    __shared__ int sc[BSTEP];
    __shared__ int hoff[BSTEP];
    __shared__ int cur[BSTEP];
    const int b = blockIdx.x;
    const int nbase = b * BSTEP;
    // p0 = sum_{i<b} (bcur[i] - i*BCAP)
    int part = 0;
    for (int i = threadIdx.x; i < b; i += 256) part += bcur[i] - i * BCAP;
    red[threadIdx.x] = part;
    __syncthreads();
    for (int d = 128; d > 0; d >>= 1) {
        if (threadIdx.x < d) red[threadIdx.x] += red[threadIdx.x + d];
        __syncthreads();
    }
    const int p0 = red[0];
    const int cnt = bcur[b] - b * BCAP;
    const unsigned* rbase = binned + (size_t)b * BCAP;
    if (threadIdx.x < BSTEP) hcnt[threadIdx.x] = 0;
    __syncthreads();
    // pass 1: per-node counts
    for (int i = threadIdx.x; i < cnt; i += 256)
        atomicAdd(&hcnt[rbase[i] >> 16], 1);
    __syncthreads();
    int v = 0;
    if (threadIdx.x < BSTEP) { v = hcnt[threadIdx.x]; sc[threadIdx.x] = v; }
    __syncthreads();
    for (int d = 1; d < BSTEP; d <<= 1) {
        int u = 0;
        if (threadIdx.x < BSTEP && threadIdx.x >= d) u = sc[threadIdx.x - d];
        __syncthreads();
        if (threadIdx.x < BSTEP) sc[threadIdx.x] += u;
        __syncthreads();
    }
    if (threadIdx.x < BSTEP) {
        int o = p0 + sc[threadIdx.x] - v;  // exclusive
        hoff[threadIdx.x] = o;
        cur[threadIdx.x] = 0;
        int n = nbase + threadIdx.x;
        if (n < NN) off[n] = o;
    }
    __syncthreads();
    // pass 2: scatter grouped by node
    for (int i = threadIdx.x; i < cnt; i += 256) {
        unsigned rec = rbase[i];
        int cl = rec >> 16;
        int pos = hoff[cl] + atomicAdd(&cur[cl], 1);
        src[pos] = (int)(rec & 0xffffu);
    }
}

// hs16[n*32+k] = bf16(dinv[n] * dot(x[n,:], W[:,k])).
// W staged per block into LDS transposed (pitch 132 — no sector blowup, R18
// lesson); each thread handles k for TWO nodes (R19/R20 lesson: load-issue bound).
__global__ void k_xw(const float* __restrict__ x, const float* __restrict__ W,
                     const int* __restrict__ off, __hip_bfloat16* __restrict__ hs16) {
    __shared__ float wt[EH * WPAD];  // 10560 B
    for (int p = threadIdx.x; p < FIN * EH; p += 256) {
        int j = p / EH, k = p - j * EH;   // p = j*EH + k (coalesced global read)
        wt[k * WPAD + j] = W[p];
    }
    __syncthreads();
    int t = blockIdx.x * blockDim.x + threadIdx.x;
    int g = t / EH;             // node-pair index
    int k = t - g * EH;
    int n0 = g * 2;
    if (n0 >= NN) return;       // NN even -> n0+1 < NN whenever n0 < NN
    const float4* xr0 = (const float4*)(x + (size_t)n0 * FIN);
    const float4* xr1 = (const float4*)(x + (size_t)(n0 + 1) * FIN);
    const float4* wr = (const float4*)(wt + k * WPAD);
    float a00 = 0.f, a01 = 0.f, a10 = 0.f, a11 = 0.f;
#pragma unroll 4
    for (int j4 = 0; j4 < FIN / 4; j4 += 2) {
        float4 w0 = wr[j4];
        float4 w1 = wr[j4 + 1];
        float4 p0 = xr0[j4];
        float4 p1 = xr0[j4 + 1];
        float4 q0 = xr1[j4];
        float4 q1 = xr1[j4 + 1];
        a00 = fmaf(p0.x, w0.x, a00); a00 = fmaf(p0.y, w0.y, a00);
        a00 = fmaf(p0.z, w0.z, a00); a00 = fmaf(p0.w, w0.w, a00);
        a01 = fmaf(p1.x, w1.x, a01); a01 = fmaf(p1.y, w1.y, a01);
        a01 = fmaf(p1.z, w1.z, a01); a01 = fmaf(p1.w, w1.w, a01);
        a10 = fmaf(q0.x, w0.x, a10); a10 = fmaf(q0.y, w0.y, a10);
        a10 = fmaf(q0.z, w0.z, a10); a10 = fmaf(q0.w, w0.w, a10);
        a11 = fmaf(q1.x, w1.x, a11); a11 = fmaf(q1.y, w1.y, a11);
        a11 = fmaf(q1.z, w1.z, a11); a11 = fmaf(q1.w, w1.w, a11);
    }
    float d0 = rsqrtf(1.0f + (float)(off[n0 + 1] - off[n0]));
    float d1 = rsqrtf(1.0f + (float)(off[n0 + 2] - off[n0 + 1]));
    hs16[(size_t)n0 * 32 + k]       = __float2bfloat16(d0 * (a00 + a01));
    hs16[(size_t)(n0 + 1) * 32 + k] = __float2bfloat16(d1 * (a10 + a11));
}

__device__ __forceinline__ float blo(unsigned u) { return __uint_as_float(u << 16); }
__device__ __forceinline__ float bhi(unsigned u) { return __uint_as_float(u & 0xffff0000u); }

// per-node gather + bias + relu; 10 lanes per node, 4-deep unrolled; zero atomics
__global__ void k_gather(const int* __restrict__ off, const int* __restrict__ src,
                         const __hip_bfloat16* __restrict__ hs16,
                         const float* __restrict__ bg, float* __restrict__ h1) {
    int t = blockIdx.x * blockDim.x + threadIdx.x;
    int n = t / 10;
    int kk = t - n * 10;     // feature pair index: handles k=2kk, 2kk+1
    if (n >= NN) return;
    const unsigned* hu = (const unsigned*)hs16;  // row stride 16 uints (32 bf16)
    unsigned self = hu[n * 16 + kk];
    float acc0 = blo(self), acc1 = bhi(self);
    int e0 = off[n], e1 = off[n + 1];
    int e = e0;
    for (; e + 3 < e1; e += 4) {
        int r0 = src[e];
        int r1 = src[e + 1];
        int r2 = src[e + 2];
        int r3 = src[e + 3];
        unsigned v0 = hu[r0 * 16 + kk];
        unsigned v1 = hu[r1 * 16 + kk];
        unsigned v2 = hu[r2 * 16 + kk];
        unsigned v3 = hu[r3 * 16 + kk];
        acc0 += blo(v0); acc1 += bhi(v0);
        acc0 += blo(v1); acc1 += bhi(v1);
        acc0 += blo(v2); acc1 += bhi(v2);
        acc0 += blo(v3); acc1 += bhi(v3);
    }
    for (; e < e1; ++e) {
        unsigned v = hu[src[e] * 16 + kk];
        acc0 += blo(v); acc1 += bhi(v);
    }
    float dinv = rsqrtf(1.0f + (float)(e1 - e0));
    float2 res;
    res.x = fmaxf(fmaf(dinv, acc0, bg[2 * kk]), 0.f);
    res.y = fmaxf(fmaf(dinv, acc1, bg[2 * kk + 1]), 0.f);
    *(float2*)(h1 + (size_t)n * EH + 2 * kk) = res;
}

// A16[n,j] = bf16(h1[n,:] @ W1[0:20, j]);
// B16[n,j] = bf16(b1[j] + h1[nid,:] @ W1[40:60, j] + h1[n,:] @ W1[20:40, j])
__global__ void k_ab(const float* __restrict__ h1, const float* __restrict__ W1,
                     const float* __restrict__ b1, const void* nid_p,
                     __hip_bfloat16* __restrict__ A16, __hip_bfloat16* __restrict__ B16) {
    int t = blockIdx.x * blockDim.x + threadIdx.x;
    int n = t >> 6;
    int j = t & 63;
    if (n >= NN) return;
    int nid = *(const int*)nid_p;  // low 32 bits valid for int32 or int64 LE
    const float* hr = h1 + (size_t)n * EH;
    const float* hn = h1 + (size_t)nid * EH;  // broadcast
    float a = 0.f, b = b1[j];
#pragma unroll
    for (int k = 0; k < EH; ++k) {
        float hv = hr[k];
        a = fmaf(hv, W1[k * DH + j], a);
        b = fmaf(hv, W1[(EH + k) * DH + j], b);
        b = fmaf(hn[k], W1[(2 * EH + k) * DH + j], b);
    }
    A16[(size_t)n * DH + j] = __float2bfloat16(a);
    B16[(size_t)n * DH + j] = __float2bfloat16(b);
}

// bucket-order edge dot: 4 lanes per record; B rows L1/L2-hot within bucket;
// writes relu-dot to stage[slot] (sequential). No ei/eps/transcendentals here.
__global__ void k_edge_b(const int* __restrict__ bcur,
                         const unsigned* __restrict__ binned,
                         const __hip_bfloat16* __restrict__ A16,
                         const __hip_bfloat16* __restrict__ B16,
                         const float* __restrict__ W2,
                         float* __restrict__ stage) {
    const int b = blockIdx.x / ESPLIT;
    const int part = blockIdx.x - b * ESPLIT;
    const int nbase = b * BSTEP;
    const int cnt = bcur[b] - b * BCAP;
    const unsigned* rbase = binned + (size_t)b * BCAP;
    float* sbase = stage + (size_t)b * BCAP;
    const int q = threadIdx.x & 3;
    const float* w = W2 + q * 16;
    for (int i = part * 64 + (threadIdx.x >> 2); i < cnt; i += 64 * ESPLIT) {
        unsigned rec = rbase[i];
        int r = (int)(rec & 0xffffu);
        int cl = (int)(rec >> 16);
        const uint4* arow = (const uint4*)(A16 + (size_t)r * DH) + q * 2;
        const uint4* brow = (const uint4*)(B16 + (size_t)(nbase + cl) * DH) + q * 2;
        float acc = 0.f;
#pragma unroll
        for (int j = 0; j < 2; ++j) {
            uint4 av = arow[j];
            uint4 bv = brow[j];
            acc = fmaf(fmaxf(blo(av.x) + blo(bv.x), 0.f), w[8 * j + 0], acc);
            acc = fmaf(fmaxf(bhi(av.x) + bhi(bv.x), 0.f), w[8 * j + 1], acc);
            acc = fmaf(fmaxf(blo(av.y) + blo(bv.y), 0.f), w[8 * j + 2], acc);
            acc = fmaf(fmaxf(bhi(av.y) + bhi(bv.y), 0.f), w[8 * j + 3], acc);
            acc = fmaf(fmaxf(blo(av.z) + blo(bv.z), 0.f), w[8 * j + 4], acc);
            acc = fmaf(fmaxf(bhi(av.z) + bhi(bv.z), 0.f), w[8 * j + 5], acc);
            acc = fmaf(fmaxf(blo(av.w) + blo(bv.w), 0.f), w[8 * j + 6], acc);
            acc = fmaf(fmaxf(bhi(av.w) + bhi(bv.w), 0.f), w[8 * j + 7], acc);
        }
        acc += __shfl_xor(acc, 1);
        acc += __shfl_xor(acc, 2);
        if (q == 0) sbase[i] = acc;
    }
}

// finalize in edge order: sequential eps/pos/out, random (cache-resident) stage read
__global__ void k_fin(const int* __restrict__ pos32, const float* __restrict__ stage,
                      const float* __restrict__ eps, const float* __restrict__ b2,
                      float* __restrict__ out) {
    int e = blockIdx.x * blockDim.x + threadIdx.x;
    if (e >= NE) return;
    float acc = stage[pos32[e]];
    float ep = eps[e];
    // ee = 0.9999 - 0.9998*ep ; 1-ee = 1e-4 + 0.9998*ep
    float ee = fmaf(-0.9998f, ep, 0.9999f);
    float om = fmaf(0.9998f, ep, 0.0001f);
    float gate = 0.69314718f * (__builtin_amdgcn_logf(ee) - __builtin_amdgcn_logf(om))
               + acc + b2[0];
    float tt = __builtin_amdgcn_exp2f(-1.44269504f * gate);
    out[e] = __builtin_amdgcn_rcpf(1.0f + tt);
}

// ---------------- launch ----------------

extern "C" void kernel_launch(void* const* d_in, const int* in_sizes, int n_in,
                              void* d_out, int out_size, void* d_ws, size_t ws_size,
                              hipStream_t stream) {
    const float* x   = (const float*)d_in[0];
    const void*  ei  = d_in[1];
    const void*  nid = d_in[2];
    const float* eps = (const float*)d_in[3];
    const float* Wg  = (const float*)d_in[4];
    const float* bg  = (const float*)d_in[5];
    const float* W1  = (const float*)d_in[6];
    const float* b1  = (const float*)d_in[7];
    const float* W2  = (const float*)d_in[8];
    const float* b2  = (const float*)d_in[9];
    float* out = (float*)d_out;

    float* ws = (float*)d_ws;
    // ALL offsets multiples of 256 floats (1 KiB): table rows stay
    // 64B-sector-aligned (R14/R15 lesson). Total ~13.06M floats = 52.3 MB.
    unsigned* binned = (unsigned*)(ws + 0);                   // 782*3072 = 2,402,304
    int*  src    = (int*)(ws + 2402560);                      // 1.6M
    int*  pos32  = (int*)(ws + 4002560);                      // 1.6M
    __hip_bfloat16* hs16 = (__hip_bfloat16*)(ws + 5602560);   // 0.8M floats
    float* h1    = ws + 6402560;                              // 1.0M (+pad)
    __hip_bfloat16* A16 = (__hip_bfloat16*)(ws + 7402752);    // 1.6M floats
    __hip_bfloat16* B16 = (__hip_bfloat16*)(ws + 9002752);    // 1.6M floats
    float* stage = ws + 10602752;                             // 2,402,304 (+pad)
    int* off     = (int*)(ws + 13005312);                     // NN+1
    int* bcur    = (int*)(ws + 13055744);                     // NBK
    int* flag    = (int*)(ws + 13056768);

    dim3 blk(256);
    const int nchunk = (NE + CHUNK - 1) / CHUNK;
    k_init<<<1, 1024, 0, stream>>>(bcur, off, flag, ei);
    k_bin<<<nchunk, blk, 0, stream>>>(ei, flag, bcur, binned, pos32);
    k_sort<<<NBK, blk, 0, stream>>>(bcur, binned, off, src);
    k_xw<<<((NN / 2) * EH + 255) / 256, blk, 0, stream>>>(x, Wg, off, hs16);
    k_gather<<<(NN * 10 + 255) / 256, blk, 0, stream>>>(off, src, hs16, bg, h1);
    k_ab<<<(NN * 64 + 255) / 256, blk, 0, stream>>>(h1, W1, b1, nid, A16, B16);
    k_edge_b<<<NBK * ESPLIT, blk, 0, stream>>>(bcur, binned, A16, B16, W2, stage);
    k_fin<<<(NE + 255) / 256, blk, 0, stream>>>(pos32, stage, eps, b2, out);
}